// Round 5
// baseline (474.046 us; speedup 1.0000x reference)
//
#include <hip/hip_runtime.h>

#define NXD 128
#define NYD 128
#define SRC_XD 64
#define SRC_YD 64
#define T_STEPSD 256
#define BATCHD 8
#define N_PROBESD 4
#define NBLK 4                 // row-blocks per batch (32 owned rows each)
#define GH 4                   // ghost depth = steps per exchange group

typedef float v2f __attribute__((ext_vector_type(2)));

// DPP cross-lane single shifts across the full wave64 (zero-fill = conv SAME).
__device__ __forceinline__ float dpp_from_lower(float v) {
    return __int_as_float(__builtin_amdgcn_update_dpp(0, __float_as_int(v), 0x138, 0xF, 0xF, true));
}
__device__ __forceinline__ float dpp_from_upper(float v) {
    return __int_as_float(__builtin_amdgcn_update_dpp(0, __float_as_int(v), 0x130, 0xF, 0xF, true));
}

//   lap = up + dn + {lf + Y.y, Y.x + rt} - 4*Y ;  Z = K*lap + (C2 + K2*Z)
#define ROW(up, dn, Yr, Zr, Kr) { \
    const float lf = dpp_from_lower((Yr).y); \
    const float rt = dpp_from_upper((Yr).x); \
    v2f cross; cross.x = lf + (Yr).y; cross.y = (Yr).x + rt; \
    const v2f lap = (up) + (dn) + cross - 4.0f * (Yr); \
    (Zr) = (Kr) * lap + (C2v + K2v * (Zr)); \
}

// 8-byte agent-scope atomic move of a v2f (device-coherent across XCDs).
__device__ __forceinline__ void gst8(unsigned long long* p, v2f v) {
    union { v2f f; unsigned long long u; } cv; cv.f = v;
    __hip_atomic_store(p, cv.u, __ATOMIC_RELAXED, __HIP_MEMORY_SCOPE_AGENT);
}
__device__ __forceinline__ v2f gld8(const unsigned long long* p) {
    union { v2f f; unsigned long long u; } cv;
    cv.u = __hip_atomic_load(p, __ATOMIC_RELAXED, __HIP_MEMORY_SCOPE_AGENT);
    return cv.f;
}

// ---------------- split kernel: 4 blocks per batch ----------------
// Local register rows i = 0..4 per wave map to rel = 5w+i; global = 32*blk-4+rel.
// Owned rel 4..35. Ghost rel 0..3 / 36..39 refreshed from neighbor blocks every
// GH=4 steps; between refreshes validity shrinks 1 row/step inward (round-1
// scheme: owned rows stay valid at EVERY step). Waves 0/7 garbage-compute their
// outermost row against a zero LDS ghost slot -- those values are provably
// never consumed while invalid and are overwritten at each exchange.
#define STEP5(Y, Z, tt, xsv) { \
    const int buf_ = (tt) & 1, nb_ = buf_ ^ 1; \
    const v2f ra = *(const v2f*)&haloBot[buf_][wa][colb]; \
    const v2f rb = *(const v2f*)&haloTop[buf_][wb][colb]; \
    ROW(Y##0, Y##2, Y##1, Z##1, k1) \
    ROW(Y##1, Y##3, Y##2, Z##2, k2) \
    ROW(Y##2, Y##4, Y##3, Z##3, k3) \
    ROW(ra,   Y##1, Y##0, Z##0, k0) \
    *(v2f*)&haloTop[nb_][w][colb] = (Z##0); \
    ROW(Y##3, rb,   Y##4, Z##4, k4) \
    if (srcA) (Z##4).x += (xsv); \
    if (srcB) (Z##1).x += (xsv); \
    *(v2f*)&haloBot[nb_][w][colb] = (Z##4); \
    if (pinz) { (Z##1) = zz; (Z##2) = zz; (Z##3) = zz; } \
    if (anyprobe) { \
        acc_0 += (Z##0) * (Z##0); acc_1 += (Z##1) * (Z##1); \
        acc_2 += (Z##2) * (Z##2); acc_3 += (Z##3) * (Z##3); \
        acc_4 += (Z##4) * (Z##4); \
    } \
    __syncthreads(); \
}

// Exchange after each 4-step group; newest field is ALWAYS in the a-registers.
// Slot map (14 rows x 128 cols, ull per lane): lowerpub 0..6 = {a4,a5,a6,a7,
// b4,b5,b6} (rel), upperpub 7..13 = {a32,a33,a34,a35,b33,b34,b35}.
// Release: publish stores -> threadfence -> barrier -> tid0 flag++.
// Acquire: relaxed poll neighbor flag >= g -> threadfence -> ghost loads.
// Parity double-buffer: producer can be at most one exchange ahead (mutual
// dependency), so 2 slots suffice.
#define EXCHG(g_) { \
    const int par_ = (g_) & 1; \
    unsigned long long* gb_ = gex + (size_t)((((bb << 2) + blk) * 2 + par_) * 14) * 64; \
    if (w == 0)      { gst8(gb_ + 0*64 + l, a4);  gst8(gb_ + 4*64 + l, b4); } \
    else if (w == 1) { gst8(gb_ + 1*64 + l, a0);  gst8(gb_ + 2*64 + l, a1); \
                       gst8(gb_ + 3*64 + l, a2);  gst8(gb_ + 5*64 + l, b0); \
                       gst8(gb_ + 6*64 + l, b1); } \
    else if (w == 6) { gst8(gb_ + 7*64 + l, a2);  gst8(gb_ + 8*64 + l, a3); \
                       gst8(gb_ + 9*64 + l, a4);  gst8(gb_ + 11*64 + l, b3); \
                       gst8(gb_ + 12*64 + l, b4); } \
    else if (w == 7) { gst8(gb_ + 10*64 + l, a0); gst8(gb_ + 13*64 + l, b0); } \
    __threadfence(); \
    __syncthreads(); \
    if (tid == 0) __hip_atomic_fetch_add(&flags[(bb << 2) + blk], 1, \
                                         __ATOMIC_RELEASE, __HIP_MEMORY_SCOPE_AGENT); \
    if (w == 0 && blk > 0) { \
        const int* fp_ = &flags[(bb << 2) + blk - 1]; int guard_ = 0; \
        while (__hip_atomic_load(fp_, __ATOMIC_RELAXED, __HIP_MEMORY_SCOPE_AGENT) < (g_) \
               && ++guard_ < 2000000) __builtin_amdgcn_s_sleep(1); \
        __threadfence(); \
        const unsigned long long* nb2_ = gex + (size_t)((((bb << 2) + blk - 1) * 2 + par_) * 14) * 64; \
        a0 = gld8(nb2_ + 7*64 + l);  a1 = gld8(nb2_ + 8*64 + l); \
        a2 = gld8(nb2_ + 9*64 + l);  a3 = gld8(nb2_ + 10*64 + l); \
        b1 = gld8(nb2_ + 11*64 + l); b2 = gld8(nb2_ + 12*64 + l); \
        b3 = gld8(nb2_ + 13*64 + l); \
    } \
    if (w == 7 && blk < NBLK - 1) { \
        const int* fp_ = &flags[(bb << 2) + blk + 1]; int guard_ = 0; \
        while (__hip_atomic_load(fp_, __ATOMIC_RELAXED, __HIP_MEMORY_SCOPE_AGENT) < (g_) \
               && ++guard_ < 2000000) __builtin_amdgcn_s_sleep(1); \
        __threadfence(); \
        const unsigned long long* nb2_ = gex + (size_t)((((bb << 2) + blk + 1) * 2 + par_) * 14) * 64; \
        a1 = gld8(nb2_ + 0*64 + l); a2 = gld8(nb2_ + 1*64 + l); \
        a3 = gld8(nb2_ + 2*64 + l); a4 = gld8(nb2_ + 3*64 + l); \
        b1 = gld8(nb2_ + 4*64 + l); b2 = gld8(nb2_ + 5*64 + l); \
        b3 = gld8(nb2_ + 6*64 + l); \
    } \
}

// grid = 32 blocks (batch = bid&7, blk = bid>>3: all 4 blocks of a batch land
// on one XCD under round-robin dispatch -> exchange stays in that XCD's L2;
// correctness does NOT depend on this, atomics are agent-scope).
__global__ __launch_bounds__(512, 2) void wave_sim_split(
        const float* __restrict__ x, const float* __restrict__ c,
        const int* __restrict__ probes, int* __restrict__ flags,
        float* __restrict__ partial, unsigned long long* __restrict__ gex)
{
    __shared__ float haloTop[2][9][NYD];   // [8] = permanent zero ghost slot
    __shared__ float haloBot[2][9][NYD];
    __shared__ float xs[T_STEPSD];

    const int tid = threadIdx.x;
    const int w = tid >> 6;                // wave 0..7, rel rows 5w..5w+4
    const int l = tid & 63;
    const int bid = blockIdx.x;
    const int bb = bid & 7;                // batch
    const int blk = bid >> 3;              // row-block 0..3
    const int colb = 2 * l;

    const float dt = 0.5f, bdamp = 0.005f;
    const float denom = 1.0f / (dt * dt) + 0.5f * bdamp / dt;
    const float inv_denom = 1.0f / denom;
    const float C2 = 2.0f * inv_denom;
    const float K2 = (-1.0f - dt * bdamp) * inv_denom;
    const float KL = dt * dt * inv_denom;
    v2f C2v; C2v.x = C2; C2v.y = C2;
    v2f K2v; K2v.x = K2; K2v.y = K2;

    for (int i = tid; i < 2 * 9 * NYD; i += 512) {
        ((float*)haloTop)[i] = 0.0f;
        ((float*)haloBot)[i] = 0.0f;
    }
    if (tid < T_STEPSD) xs[tid] = x[tid * BATCHD + bb];

    // K for local rows (ghost rows load their REAL global c; clamp only hits
    // physically-nonexistent rows whose results are pinned/unused)
#define LOADK(r) \
    v2f k##r; { \
        int grow = blk * 32 - 4 + 5 * w + (r); \
        grow = grow < 0 ? 0 : (grow > NXD - 1 ? NXD - 1 : grow); \
        const v2f cc = *(const v2f*)&c[grow * NYD + colb]; \
        k##r = KL * cc * cc; \
    }
    LOADK(0) LOADK(1) LOADK(2) LOADK(3) LOADK(4)
#undef LOADK

    v2f zz; zz.x = 0.0f; zz.y = 0.0f;
    v2f a0 = zz, a1 = zz, a2 = zz, a3 = zz, a4 = zz;
    v2f b0 = zz, b1 = zz, b2 = zz, b3 = zz, b4 = zz;
    v2f acc_0 = zz, acc_1 = zz, acc_2 = zz, acc_3 = zz, acc_4 = zz;

    // probes (wave-uniform coords): rel = (px&31)+4, wave = rel/5, local = rel%5
    const int px0 = probes[0] & 127, py0 = probes[1] & 127;
    const int px1 = probes[2] & 127, py1 = probes[3] & 127;
    const int px2 = probes[4] & 127, py2 = probes[5] & 127;
    const int px3 = probes[6] & 127, py3 = probes[7] & 127;
    const int rl0 = (px0 & 31) + 4, rl1 = (px1 & 31) + 4,
              rl2 = (px2 & 31) + 4, rl3 = (px3 & 31) + 4;
    const bool own0 = ((px0 >> 5) == blk) && ((rl0 / 5) == w) && ((py0 >> 1) == l);
    const bool own1 = ((px1 >> 5) == blk) && ((rl1 / 5) == w) && ((py1 >> 1) == l);
    const bool own2 = ((px2 >> 5) == blk) && ((rl2 / 5) == w) && ((py2 >> 1) == l);
    const bool own3 = ((px3 >> 5) == blk) && ((rl3 / 5) == w) && ((py3 >> 1) == l);
    const bool anyprobe = __ballot(own0 | own1 | own2 | own3) != 0ULL;
    const int lr0 = __builtin_amdgcn_readfirstlane(rl0 % 5);
    const int lr1 = __builtin_amdgcn_readfirstlane(rl1 % 5);
    const int lr2 = __builtin_amdgcn_readfirstlane(rl2 % 5);
    const int lr3 = __builtin_amdgcn_readfirstlane(rl3 % 5);
    const int pel0 = py0 & 1, pel1 = py1 & 1, pel2 = py2 & 1, pel3 = py3 & 1;

    // source row 64 col 64: owner blk2/w0/local4; ghost replica blk1/w7/local1.
    // Both add x[t] so replica stays bit-identical to owner.
    const bool srcA = (blk == 2) && (w == 0) && (l == (SRC_YD >> 1));
    const bool srcB = (blk == 1) && (w == 7) && (l == (SRC_YD >> 1));
    // physical zero-padding rows (global <0 or >127): pin to zero every step
    const bool pinz = (blk == 0 && w == 0) || (blk == NBLK - 1 && w == 7);

    const int wa = (w == 0) ? 8 : w - 1;
    const int wb = (w == 7) ? 8 : w + 1;

    __syncthreads();

    int g = 0;
#pragma unroll 1
    for (int t = 0; t < T_STEPSD; t += 4) {
        const float4 xq = *(const float4*)&xs[t];
        STEP5(a, b, t,     xq.x)
        STEP5(b, a, t + 1, xq.y)
        STEP5(a, b, t + 2, xq.z)
        STEP5(b, a, t + 3, xq.w)
        if (t + 4 < T_STEPSD) { ++g; EXCHG(g) }
    }

#define PSEL5(ro, pv) switch (ro) { \
    case 0: pv = acc_0; break; case 1: pv = acc_1; break; \
    case 2: pv = acc_2; break; case 3: pv = acc_3; break; \
    default: pv = acc_4; break; }
    if (own0) { v2f pv; PSEL5(lr0, pv) partial[bb * N_PROBESD + 0] = pel0 ? pv.y : pv.x; }
    if (own1) { v2f pv; PSEL5(lr1, pv) partial[bb * N_PROBESD + 1] = pel1 ? pv.y : pv.x; }
    if (own2) { v2f pv; PSEL5(lr2, pv) partial[bb * N_PROBESD + 2] = pel2 ? pv.y : pv.x; }
    if (own3) { v2f pv; PSEL5(lr3, pv) partial[bb * N_PROBESD + 3] = pel3 ? pv.y : pv.x; }
#undef PSEL5
}

// ---------------- fallback: round-4 single-CU-per-batch kernel ----------------
#define PSEL8(ro, Z, pv) switch (ro) { \
    case 0: pv = (Z##0); break; case 1: pv = (Z##1); break; \
    case 2: pv = (Z##2); break; case 3: pv = (Z##3); break; \
    case 4: pv = (Z##4); break; case 5: pv = (Z##5); break; \
    case 6: pv = (Z##6); break; default: pv = (Z##7); break; }

#define STEP8(Y, Z, tt, xsv) { \
    const int buf_ = (tt) & 1, nb_ = buf_ ^ 1; \
    const v2f ra = *(const v2f*)&haloBot[buf_][wa][colb]; \
    const v2f rb = *(const v2f*)&haloTop[buf_][wb][colb]; \
    ROW(Y##1,  Y##3,  Y##2,  Z##2,  k2) \
    ROW(Y##2,  Y##4,  Y##3,  Z##3,  k3) \
    ROW(Y##3,  Y##5,  Y##4,  Z##4,  k4) \
    ROW(ra,    Y##1,  Y##0,  Z##0,  k0) \
    if (has_src) { if (own_src) (Z##0).x += (xsv); } \
    *(v2f*)&haloTop[nb_][w][colb] = (Z##0); \
    ROW(Y##6,  rb,    Y##7,  Z##7,  k7) \
    *(v2f*)&haloBot[nb_][w][colb] = (Z##7); \
    ROW(Y##0,  Y##2,  Y##1,  Z##1,  k1) \
    ROW(Y##4,  Y##6,  Y##5,  Z##5,  k5) \
    ROW(Y##5,  Y##7,  Y##6,  Z##6,  k6) \
    if (anyprobe) { \
        acc8_0 += (Z##0) * (Z##0); acc8_1 += (Z##1) * (Z##1); \
        acc8_2 += (Z##2) * (Z##2); acc8_3 += (Z##3) * (Z##3); \
        acc8_4 += (Z##4) * (Z##4); acc8_5 += (Z##5) * (Z##5); \
        acc8_6 += (Z##6) * (Z##6); acc8_7 += (Z##7) * (Z##7); \
    } \
    __syncthreads(); \
}

__global__ __launch_bounds__(1024, 4) void wave_sim_full(
        const float* __restrict__ x, const float* __restrict__ c,
        const int* __restrict__ probes, float* __restrict__ partial)
{
    __shared__ float haloTop[2][17][NYD];
    __shared__ float haloBot[2][17][NYD];
    __shared__ float xs[T_STEPSD];

    const int tid = threadIdx.x;
    const int w = tid >> 6;
    const int l = tid & 63;
    const int b = blockIdx.x;

    const float dt = 0.5f, bdamp = 0.005f;
    const float denom = 1.0f / (dt * dt) + 0.5f * bdamp / dt;
    const float inv_denom = 1.0f / denom;
    const float C2 = 2.0f * inv_denom;
    const float K2 = (-1.0f - dt * bdamp) * inv_denom;
    const float KL = dt * dt * inv_denom;
    v2f C2v; C2v.x = C2; C2v.y = C2;
    v2f K2v; K2v.x = K2; K2v.y = K2;

    for (int i = tid; i < 2 * 17 * NYD; i += 1024) {
        ((float*)haloTop)[i] = 0.0f;
        ((float*)haloBot)[i] = 0.0f;
    }
    if (tid < T_STEPSD) xs[tid] = x[tid * BATCHD + b];

    const int rowbase = w * 8;
    const int colb = 2 * l;
#define LOADK(r) \
    v2f k##r; { \
        const v2f cc = *(const v2f*)&c[(rowbase + r) * NYD + colb]; \
        k##r = KL * cc * cc; \
    }
    LOADK(0) LOADK(1) LOADK(2) LOADK(3) LOADK(4) LOADK(5) LOADK(6) LOADK(7)
#undef LOADK

    v2f zz; zz.x = 0.0f; zz.y = 0.0f;
    v2f a0 = zz, a1 = zz, a2 = zz, a3 = zz, a4 = zz, a5 = zz, a6 = zz, a7 = zz;
    v2f b0 = zz, b1 = zz, b2 = zz, b3 = zz, b4 = zz, b5 = zz, b6 = zz, b7 = zz;
    v2f acc8_0 = zz, acc8_1 = zz, acc8_2 = zz, acc8_3 = zz,
        acc8_4 = zz, acc8_5 = zz, acc8_6 = zz, acc8_7 = zz;

    const int px0 = probes[0] & 127, py0 = probes[1] & 127;
    const int px1 = probes[2] & 127, py1 = probes[3] & 127;
    const int px2 = probes[4] & 127, py2 = probes[5] & 127;
    const int px3 = probes[6] & 127, py3 = probes[7] & 127;
    const bool own0 = ((px0 >> 3) == w) && ((py0 >> 1) == l);
    const bool own1 = ((px1 >> 3) == w) && ((py1 >> 1) == l);
    const bool own2 = ((px2 >> 3) == w) && ((py2 >> 1) == l);
    const bool own3 = ((px3 >> 3) == w) && ((py3 >> 1) == l);
    const bool anyprobe = __ballot(own0 | own1 | own2 | own3) != 0ULL;
    const int pro0s = __builtin_amdgcn_readfirstlane(px0 & 7);
    const int pro1s = __builtin_amdgcn_readfirstlane(px1 & 7);
    const int pro2s = __builtin_amdgcn_readfirstlane(px2 & 7);
    const int pro3s = __builtin_amdgcn_readfirstlane(px3 & 7);
    const int pel0 = py0 & 1, pel1 = py1 & 1, pel2 = py2 & 1, pel3 = py3 & 1;

    const bool has_src = (w == (SRC_XD >> 3));
    const bool own_src = has_src && (l == (SRC_YD >> 1));

    const int wa = (w == 0) ? 16 : w - 1;
    const int wb = (w == 15) ? 16 : w + 1;

    __syncthreads();

#pragma unroll 1
    for (int t = 0; t < T_STEPSD; t += 2) {
        const v2f xp = *(const v2f*)&xs[t];
        STEP8(a, b, t, xp.x)
        STEP8(b, a, t + 1, xp.y)
    }

    if (own0) { v2f pv; PSEL8(pro0s, acc8_, pv) partial[b * N_PROBESD + 0] = pel0 ? pv.y : pv.x; }
    if (own1) { v2f pv; PSEL8(pro1s, acc8_, pv) partial[b * N_PROBESD + 1] = pel1 ? pv.y : pv.x; }
    if (own2) { v2f pv; PSEL8(pro2s, acc8_, pv) partial[b * N_PROBESD + 2] = pel2 ? pv.y : pv.x; }
    if (own3) { v2f pv; PSEL8(pro3s, acc8_, pv) partial[b * N_PROBESD + 3] = pel3 ? pv.y : pv.x; }
}

__global__ void reduce_k(const float* __restrict__ partial, float* __restrict__ out) {
    const int p = threadIdx.x;
    if (p < N_PROBESD) {
        float s = 0.0f, tot = 0.0f;
        for (int bb = 0; bb < BATCHD; ++bb) s += partial[bb * N_PROBESD + p];
        for (int i = 0; i < BATCHD * N_PROBESD; ++i) tot += partial[i];
        out[p] = s / tot;
    }
}

// d_ws layout: [0..127] flags (32 ints, zeroed per launch) | [128..255] partial
// (32 floats) | [256..] gex exchange buffer 8*4*2*14*128 floats (~459 KB).
extern "C" void kernel_launch(void* const* d_in, const int* in_sizes, int n_in,
                              void* d_out, int out_size, void* d_ws, size_t ws_size,
                              hipStream_t stream) {
    const float* x      = (const float*)d_in[0];
    const float* c      = (const float*)d_in[1];
    const int*   probes = (const int*)d_in[2];
    float* out = (float*)d_out;
    float* partial = (float*)d_ws + 32;

    const size_t need = 256 + (size_t)BATCHD * NBLK * 2 * 14 * NYD * sizeof(float);
    if (ws_size >= need) {
        hipMemsetAsync(d_ws, 0, 128, stream);   // flags only; stream-ordered, capture-safe
        wave_sim_split<<<BATCHD * NBLK, 512, 0, stream>>>(
            x, c, probes, (int*)d_ws, partial,
            (unsigned long long*)((char*)d_ws + 256));
    } else {
        wave_sim_full<<<BATCHD, 1024, 0, stream>>>(x, c, probes, partial);
    }
    reduce_k<<<1, 64, 0, stream>>>(partial, out);
}

// Round 7
// 125.037 us; speedup vs baseline: 3.7912x; 3.7912x over previous
//
#include <hip/hip_runtime.h>

#define NXD 128
#define NYD 128
#define SRC_XD 64
#define SRC_YD 64
#define T_STEPSD 256
#define BATCHD 8
#define N_PROBESD 4
#define NSLICE 8               // atomic-contention slices for probe traces

typedef float v2f __attribute__((ext_vector_type(2)));

// DPP cross-lane single shifts across the full wave64 (zero-fill = conv SAME).
__device__ __forceinline__ float dpp_from_lower(float v) {
    return __int_as_float(__builtin_amdgcn_update_dpp(0, __float_as_int(v), 0x138, 0xF, 0xF, true));
}
__device__ __forceinline__ float dpp_from_upper(float v) {
    return __int_as_float(__builtin_amdgcn_update_dpp(0, __float_as_int(v), 0x130, 0xF, 0xF, true));
}

// ======================= SPECTRAL PATH (c == 1) =======================
// Reference step: y' = (2.0 + dt^2 lap(y1) - (1+dt*b) y2)/denom  (+src).
// NOTE the 2.0 is a CONSTANT FIELD added every step (not 2*y1!) -- round-6
// missed this. DST-I in x (modes S[i,k]=sin(pi(k+1)(i+1)/129), zero-Dirichlet
// == conv-SAME zero rows):
//   u'_k[j] = C1*u_k[j] + C3*(u_k[j-1]+u_k[j+1]) + C2*uo_k[j] + f_k + b_k*x_t*d_{j,64}
//   C1 = dt^2(lam_k - 2)/denom   (the -2 is Ly's diagonal; NO "+2" term)
//   C3 = dt^2/denom,  C2 = -(1+dt*b)/denom
//   f_k = (2/denom)*g_k,  g_k = (2/129)*cot(pi*m/258) for odd m=k+1, else 0
//       (DST-I of the ones field: sum_{n=1}^{128} sin(pi m n/129) = cot(pi m/258), odd m)
//   b_k = (2/129)*sin(pi m * 65/129)   (source add AFTER the division)
// One wave64 per (mode k, batch): 2 cols/lane, DPP column stencil, no barriers.
// Probe traces p_j(t) = sum_k S[px_j,k] * u_k[py_j](t), accumulated via f32
// atomics into NSLICE=8 contention slices (s=k&7, slices 32KB apart -> distinct
// L2 lines; 16-way same-address contention instead of 128).

__global__ void check_c(const float* __restrict__ c, int* __restrict__ flag) {
    const int i = blockIdx.x * 256 + threadIdx.x;
    const bool bad = (c[i] != 1.0f);
    if (__ballot(bad) != 0ULL) {
        if ((threadIdx.x & 63) == 0) atomicOr(flag, 1);
    }
}

__global__ __launch_bounds__(256) void spectral_evolve(
        const float* __restrict__ x,        // (T,B)
        const int*   __restrict__ probes,   // (4,2) int32
        const int*   __restrict__ flag,
        float*       __restrict__ pbuf)     // (8 slices,4,8,256) probe traces
{
    if (*flag != 0) return;                 // c not uniform -> fallback path
    __shared__ float xls[T_STEPSD + 2];

    const int tid = threadIdx.x;
    const int l = tid & 63;
    const int wg = blockIdx.x * 4 + (tid >> 6);  // global wave id 0..1023
    const int bb = blockIdx.x >> 5;              // batch (block-uniform: 4|128)
    const int kx = wg & 127;                     // mode index (wave-uniform)
    const int sl = kx & (NSLICE - 1);            // contention slice

    if (tid < T_STEPSD) xls[tid] = x[tid * BATCHD + bb];
    if (tid < 2) xls[T_STEPSD + tid] = 0.0f;     // pad for 2-ahead prefetch

    const float dt = 0.5f, bd = 0.005f;
    const float denom = 1.0f / (dt * dt) + 0.5f * bd / dt;   // 4.005
    const int m = kx + 1;
    // lam = -4 sin^2(pi m/258)
    const float s1 = sinpif((float)m / 258.0f);
    const float lam = -4.0f * s1 * s1;
    const float C1s = (dt * dt * (lam - 2.0f)) / denom;
    const float C3s = (dt * dt) / denom;
    const float C2s = -(1.0f + dt * bd) / denom;
    // constant-field forcing (transform of the "+2.0" term)
    const float g = (m & 1) ? (2.0f / 129.0f) *
                    (cospif((float)m / 258.0f) / sinpif((float)m / 258.0f)) : 0.0f;
    const float fk = 2.0f * g / denom;
    // source coefficient
    const float bk = (2.0f / 129.0f) *
                     sinpif((float)((m * (SRC_XD + 1)) % 258) / 129.0f);

    v2f C1v; C1v.x = C1s; C1v.y = C1s;
    v2f C3v; C3v.x = C3s; C3v.y = C3s;
    v2f C2v; C2v.x = C2s; C2v.y = C2s;
    v2f fv;  fv.x = fk;  fv.y = fk;
    v2f zz;  zz.x = 0.0f; zz.y = 0.0f;
    v2f svec = zz; if (l == (SRC_YD >> 1)) svec.x = bk;   // col 64 = lane32.x

    // probes (int32 pairs; JAX int64 demotes to int32 without x64)
    const int px0 = probes[0] & 127, py0 = probes[1] & 127;
    const int px1 = probes[2] & 127, py1 = probes[3] & 127;
    const int px2 = probes[4] & 127, py2 = probes[5] & 127;
    const int px3 = probes[6] & 127, py3 = probes[7] & 127;
    const float wx0 = sinpif((float)((m * (px0 + 1)) % 258) / 129.0f);
    const float wx1 = sinpif((float)((m * (px1 + 1)) % 258) / 129.0f);
    const float wx2 = sinpif((float)((m * (px2 + 1)) % 258) / 129.0f);
    const float wx3 = sinpif((float)((m * (px3 + 1)) % 258) / 129.0f);
    const int pyl0 = py0 >> 1, pel0 = py0 & 1;
    const int pyl1 = py1 >> 1, pel1 = py1 & 1;
    const int pyl2 = py2 >> 1, pel2 = py2 & 1;
    const int pyl3 = py3 >> 1, pel3 = py3 & 1;
    float* const pb0 = pbuf + ((sl * N_PROBESD + 0) * BATCHD + bb) * T_STEPSD;
    float* const pb1 = pbuf + ((sl * N_PROBESD + 1) * BATCHD + bb) * T_STEPSD;
    float* const pb2 = pbuf + ((sl * N_PROBESD + 2) * BATCHD + bb) * T_STEPSD;
    float* const pb3 = pbuf + ((sl * N_PROBESD + 3) * BATCHD + bb) * T_STEPSD;

    __syncthreads();

    v2f u = zz, uo = zz;
    v2f xc; xc.x = xls[0]; xc.y = xls[1];

#define SSTEP(xv, tt) { \
    const float lf = dpp_from_lower(u.y); \
    const float rt = dpp_from_upper(u.x); \
    v2f cross; cross.x = lf + u.y; cross.y = u.x + rt; \
    const v2f r = C1v * u + C3v * cross + C2v * uo + svec * (xv) + fv; \
    uo = u; u = r; \
    if (l == pyl0) __hip_atomic_fetch_add(pb0 + (tt), wx0 * (pel0 ? u.y : u.x), \
                        __ATOMIC_RELAXED, __HIP_MEMORY_SCOPE_AGENT); \
    if (l == pyl1) __hip_atomic_fetch_add(pb1 + (tt), wx1 * (pel1 ? u.y : u.x), \
                        __ATOMIC_RELAXED, __HIP_MEMORY_SCOPE_AGENT); \
    if (l == pyl2) __hip_atomic_fetch_add(pb2 + (tt), wx2 * (pel2 ? u.y : u.x), \
                        __ATOMIC_RELAXED, __HIP_MEMORY_SCOPE_AGENT); \
    if (l == pyl3) __hip_atomic_fetch_add(pb3 + (tt), wx3 * (pel3 ? u.y : u.x), \
                        __ATOMIC_RELAXED, __HIP_MEMORY_SCOPE_AGENT); \
}

#pragma unroll 1
    for (int t = 0; t < T_STEPSD; t += 2) {
        const v2f xn = *(const v2f*)&xls[t + 2];   // 2-ahead: hides ds latency
        SSTEP(xc.x, t)
        SSTEP(xc.y, t + 1)
        xc = xn;
    }
#undef SSTEP
}

__global__ void spectral_reduce(const float* __restrict__ pbuf,
                                const int* __restrict__ flag,
                                float* __restrict__ partial) {
    if (*flag != 0) return;
    const int tid = threadIdx.x;       // 1024 threads: 32 (j,b) x 32 lanes
    const int jb = tid >> 5;           // j = jb>>3, b = jb&7
    const int j = jb >> 3, b = jb & 7;
    const int ln = tid & 31;
    float acc = 0.0f;
#pragma unroll
    for (int i = 0; i < 8; ++i) {
        const int t = ln * 8 + i;
        float v = 0.0f;
#pragma unroll
        for (int s = 0; s < NSLICE; ++s)
            v += pbuf[((s * N_PROBESD + j) * BATCHD + b) * T_STEPSD + t];
        acc += v * v;
    }
    for (int off = 16; off; off >>= 1) acc += __shfl_down(acc, off, 32);
    if (ln == 0) partial[b * N_PROBESD + j] = acc;
}

// ================= FALLBACK PATH (arbitrary c): round-4 kernel =================
//   lap = up + dn + {lf + Y.y, Y.x + rt} - 4*Y ;  Z = K*lap + (C2 + K2*Z)
#define ROW(up, dn, Yr, Zr, Kr) { \
    const float lf = dpp_from_lower((Yr).y); \
    const float rt = dpp_from_upper((Yr).x); \
    v2f cross; cross.x = lf + (Yr).y; cross.y = (Yr).x + rt; \
    const v2f lap = (up) + (dn) + cross - 4.0f * (Yr); \
    (Zr) = (Kr) * lap + (C2v + K2v * (Zr)); \
}

#define PSEL8(ro, Z, pv) switch (ro) { \
    case 0: pv = (Z##0); break; case 1: pv = (Z##1); break; \
    case 2: pv = (Z##2); break; case 3: pv = (Z##3); break; \
    case 4: pv = (Z##4); break; case 5: pv = (Z##5); break; \
    case 6: pv = (Z##6); break; default: pv = (Z##7); break; }

#define STEP8(Y, Z, tt, xsv) { \
    const int buf_ = (tt) & 1, nb_ = buf_ ^ 1; \
    const v2f ra = *(const v2f*)&haloBot[buf_][wa][colb]; \
    const v2f rb = *(const v2f*)&haloTop[buf_][wb][colb]; \
    ROW(Y##1,  Y##3,  Y##2,  Z##2,  k2) \
    ROW(Y##2,  Y##4,  Y##3,  Z##3,  k3) \
    ROW(Y##3,  Y##5,  Y##4,  Z##4,  k4) \
    ROW(ra,    Y##1,  Y##0,  Z##0,  k0) \
    if (has_src) { if (own_src) (Z##0).x += (xsv); } \
    *(v2f*)&haloTop[nb_][w][colb] = (Z##0); \
    ROW(Y##6,  rb,    Y##7,  Z##7,  k7) \
    *(v2f*)&haloBot[nb_][w][colb] = (Z##7); \
    ROW(Y##0,  Y##2,  Y##1,  Z##1,  k1) \
    ROW(Y##4,  Y##6,  Y##5,  Z##5,  k5) \
    ROW(Y##5,  Y##7,  Y##6,  Z##6,  k6) \
    if (anyprobe) { \
        acc8_0 += (Z##0) * (Z##0); acc8_1 += (Z##1) * (Z##1); \
        acc8_2 += (Z##2) * (Z##2); acc8_3 += (Z##3) * (Z##3); \
        acc8_4 += (Z##4) * (Z##4); acc8_5 += (Z##5) * (Z##5); \
        acc8_6 += (Z##6) * (Z##6); acc8_7 += (Z##7) * (Z##7); \
    } \
    __syncthreads(); \
}

__global__ __launch_bounds__(1024, 4) void wave_sim_full(
        const float* __restrict__ x, const float* __restrict__ c,
        const int* __restrict__ probes, float* __restrict__ partial,
        const int* __restrict__ flag)
{
    if (flag && *flag == 0) return;     // spectral path handled it

    __shared__ float haloTop[2][17][NYD];
    __shared__ float haloBot[2][17][NYD];
    __shared__ float xs[T_STEPSD];

    const int tid = threadIdx.x;
    const int w = tid >> 6;
    const int l = tid & 63;
    const int b = blockIdx.x;

    const float dt = 0.5f, bdamp = 0.005f;
    const float denom = 1.0f / (dt * dt) + 0.5f * bdamp / dt;
    const float inv_denom = 1.0f / denom;
    const float C2 = 2.0f * inv_denom;
    const float K2 = (-1.0f - dt * bdamp) * inv_denom;
    const float KL = dt * dt * inv_denom;
    v2f C2v; C2v.x = C2; C2v.y = C2;
    v2f K2v; K2v.x = K2; K2v.y = K2;

    for (int i = tid; i < 2 * 17 * NYD; i += 1024) {
        ((float*)haloTop)[i] = 0.0f;
        ((float*)haloBot)[i] = 0.0f;
    }
    if (tid < T_STEPSD) xs[tid] = x[tid * BATCHD + b];

    const int rowbase = w * 8;
    const int colb = 2 * l;
#define LOADK(r) \
    v2f k##r; { \
        const v2f cc = *(const v2f*)&c[(rowbase + r) * NYD + colb]; \
        k##r = KL * cc * cc; \
    }
    LOADK(0) LOADK(1) LOADK(2) LOADK(3) LOADK(4) LOADK(5) LOADK(6) LOADK(7)
#undef LOADK

    v2f zz; zz.x = 0.0f; zz.y = 0.0f;
    v2f a0 = zz, a1 = zz, a2 = zz, a3 = zz, a4 = zz, a5 = zz, a6 = zz, a7 = zz;
    v2f b0 = zz, b1 = zz, b2 = zz, b3 = zz, b4 = zz, b5 = zz, b6 = zz, b7 = zz;
    v2f acc8_0 = zz, acc8_1 = zz, acc8_2 = zz, acc8_3 = zz,
        acc8_4 = zz, acc8_5 = zz, acc8_6 = zz, acc8_7 = zz;

    const int px0 = probes[0] & 127, py0 = probes[1] & 127;
    const int px1 = probes[2] & 127, py1 = probes[3] & 127;
    const int px2 = probes[4] & 127, py2 = probes[5] & 127;
    const int px3 = probes[6] & 127, py3 = probes[7] & 127;
    const bool own0 = ((px0 >> 3) == w) && ((py0 >> 1) == l);
    const bool own1 = ((px1 >> 3) == w) && ((py1 >> 1) == l);
    const bool own2 = ((px2 >> 3) == w) && ((py2 >> 1) == l);
    const bool own3 = ((px3 >> 3) == w) && ((py3 >> 1) == l);
    const bool anyprobe = __ballot(own0 | own1 | own2 | own3) != 0ULL;
    const int pro0s = __builtin_amdgcn_readfirstlane(px0 & 7);
    const int pro1s = __builtin_amdgcn_readfirstlane(px1 & 7);
    const int pro2s = __builtin_amdgcn_readfirstlane(px2 & 7);
    const int pro3s = __builtin_amdgcn_readfirstlane(px3 & 7);
    const int pel0 = py0 & 1, pel1 = py1 & 1, pel2 = py2 & 1, pel3 = py3 & 1;

    const bool has_src = (w == (SRC_XD >> 3));
    const bool own_src = has_src && (l == (SRC_YD >> 1));

    const int wa = (w == 0) ? 16 : w - 1;
    const int wb = (w == 15) ? 16 : w + 1;

    __syncthreads();

#pragma unroll 1
    for (int t = 0; t < T_STEPSD; t += 2) {
        const v2f xp = *(const v2f*)&xs[t];
        STEP8(a, b, t, xp.x)
        STEP8(b, a, t + 1, xp.y)
    }

    if (own0) { v2f pv; PSEL8(pro0s, acc8_, pv) partial[b * N_PROBESD + 0] = pel0 ? pv.y : pv.x; }
    if (own1) { v2f pv; PSEL8(pro1s, acc8_, pv) partial[b * N_PROBESD + 1] = pel1 ? pv.y : pv.x; }
    if (own2) { v2f pv; PSEL8(pro2s, acc8_, pv) partial[b * N_PROBESD + 2] = pel2 ? pv.y : pv.x; }
    if (own3) { v2f pv; PSEL8(pro3s, acc8_, pv) partial[b * N_PROBESD + 3] = pel3 ? pv.y : pv.x; }
}

__global__ void reduce_k(const float* __restrict__ partial, float* __restrict__ out) {
    const int p = threadIdx.x;
    if (p < N_PROBESD) {
        float s = 0.0f, tot = 0.0f;
        for (int bb = 0; bb < BATCHD; ++bb) s += partial[bb * N_PROBESD + p];
        for (int i = 0; i < BATCHD * N_PROBESD; ++i) tot += partial[i];
        out[p] = s / tot;
    }
}

// d_ws layout (spectral path):
//   [0..4) flag | [256..262400) pbuf (8*4*8*256 f32 = 256KB) | then partial (32 f32)
// r5 proved ws_size >= 459008, so the spectral branch is taken.
extern "C" void kernel_launch(void* const* d_in, const int* in_sizes, int n_in,
                              void* d_out, int out_size, void* d_ws, size_t ws_size,
                              hipStream_t stream) {
    const float* x      = (const float*)d_in[0];
    const float* c      = (const float*)d_in[1];
    const int*   probes = (const int*)d_in[2];
    float* out = (float*)d_out;

    const size_t pbuf_off = 256;
    const size_t pbuf_bytes = (size_t)NSLICE * N_PROBESD * BATCHD * T_STEPSD * sizeof(float);
    const size_t part_off = pbuf_off + pbuf_bytes;
    const size_t need = part_off + 32 * sizeof(float);
    if (ws_size >= need) {
        int*   flag    = (int*)d_ws;
        float* pbuf    = (float*)((char*)d_ws + pbuf_off);
        float* partial = (float*)((char*)d_ws + part_off);
        hipMemsetAsync(d_ws, 0, need, stream);      // flag + pbuf + partial
        check_c<<<64, 256, 0, stream>>>(c, flag);
        spectral_evolve<<<256, 256, 0, stream>>>(x, probes, flag, pbuf);
        spectral_reduce<<<1, 1024, 0, stream>>>(pbuf, flag, partial);
        wave_sim_full<<<BATCHD, 1024, 0, stream>>>(x, c, probes, partial, flag);
        reduce_k<<<1, 64, 0, stream>>>(partial, out);
    } else {
        float* partial = (float*)d_ws;
        wave_sim_full<<<BATCHD, 1024, 0, stream>>>(x, c, probes, partial, nullptr);
        reduce_k<<<1, 64, 0, stream>>>(partial, out);
    }
}

// Round 10
// 92.471 us; speedup vs baseline: 5.1264x; 1.3522x over previous
//
#include <hip/hip_runtime.h>

#define NXD 128
#define NYD 128
#define SRC_XD 64
#define SRC_YD 64
#define T_STEPSD 256
#define BATCHD 8
#define N_PROBESD 4
#define NSLICE 8               // atomic-contention slices for probe traces

typedef float v2f __attribute__((ext_vector_type(2)));

// DPP cross-lane single shifts across the full wave64 (zero-fill = conv SAME).
__device__ __forceinline__ float dpp_from_lower(float v) {
    return __int_as_float(__builtin_amdgcn_update_dpp(0, __float_as_int(v), 0x138, 0xF, 0xF, true));
}
__device__ __forceinline__ float dpp_from_upper(float v) {
    return __int_as_float(__builtin_amdgcn_update_dpp(0, __float_as_int(v), 0x130, 0xF, 0xF, true));
}

// Capture lane srcl's value of v into lane dstl of trace register tr.
// r8: __builtin_amdgcn_writelane doesn't exist on this ROCm. r9: inline-asm
// v_writelane with SGPR data + SGPR lane violates the 1-SGPR constant-bus
// rule. Portable fix: readlane -> SGPR broadcast, then a predicated move
// (v_cmp vcc + v_cndmask; vcc doesn't count against the constant bus).
__device__ __forceinline__ void lane_store(float& tr, float v, int srcl, int dstl, int l) {
    const float sv = __int_as_float(__builtin_amdgcn_readlane(__float_as_int(v), srcl));
    if (l == dstl) tr = sv;
}

// ======================= SPECTRAL PATH (c == 1) =======================
// Reference step: y' = (2.0 + dt^2 lap(y1) - (1+dt*b) y2)/denom  (+src).
// The 2.0 is a CONSTANT FIELD added every step. DST-I in x diagonalizes:
//   u'_k[j] = C1*u + C3*(u[j-1]+u[j+1]) + C2*uo + f_k + b_k*x_t*d_{j,64}
// One wave64 per (mode k, batch). r7 lesson: per-step agent-scope atomics are
// memory-side RMWs (32 MB WRITE_SIZE, 65 us of a 65 us kernel). Now: probe
// values accumulate in REGISTERS (lane t&63 of a trace reg via readlane +
// predicated move), spill to LDS every 64 steps, block reduces its 4 modes
// (wx-weighted) after the loop, and issues ONE coalesced atomic burst per
// (probe,chunk): 262K lane-RMWs total (was 1M), 4-way contention (was 16),
// all issued at kernel end where they pipeline and drain for free.

__global__ void check_c(const float* __restrict__ c, int* __restrict__ flag) {
    const int i = blockIdx.x * 256 + threadIdx.x;
    const bool bad = (c[i] != 1.0f);
    if (__ballot(bad) != 0ULL) {
        if ((threadIdx.x & 63) == 0) atomicOr(flag, 1);
    }
}

__global__ __launch_bounds__(256) void spectral_evolve(
        const float* __restrict__ x,        // (T,B)
        const int*   __restrict__ probes,   // (4,2) int32
        const int*   __restrict__ flag,
        float*       __restrict__ pbuf)     // (8 slices,4,8,256) probe traces
{
    if (*flag != 0) return;                 // c not uniform -> fallback path
    __shared__ float xls[T_STEPSD + 2];
    __shared__ float ltr[4][N_PROBESD][4][64];  // [wave][probe][chunk][lane] 16KB
    __shared__ float lwx[4][N_PROBESD];         // per-wave probe weights

    const int tid = threadIdx.x;
    const int l = tid & 63;
    const int wid = tid >> 6;
    const int wg = blockIdx.x * 4 + wid;         // global wave id 0..1023
    const int bb = blockIdx.x >> 5;              // batch (block-uniform: 4|128)
    const int kx = wg & 127;                     // mode index (wave-uniform)

    if (tid < T_STEPSD) xls[tid] = x[tid * BATCHD + bb];
    if (tid < 2) xls[T_STEPSD + tid] = 0.0f;     // pad for 2-ahead prefetch

    const float dt = 0.5f, bd = 0.005f;
    const float denom = 1.0f / (dt * dt) + 0.5f * bd / dt;   // 4.005
    const int m = kx + 1;
    // lam = -4 sin^2(pi m/258)
    const float s1 = sinpif((float)m / 258.0f);
    const float lam = -4.0f * s1 * s1;
    const float C1s = (dt * dt * (lam - 2.0f)) / denom;
    const float C3s = (dt * dt) / denom;
    const float C2s = -(1.0f + dt * bd) / denom;
    // constant-field forcing (transform of the "+2.0" term)
    const float g = (m & 1) ? (2.0f / 129.0f) *
                    (cospif((float)m / 258.0f) / sinpif((float)m / 258.0f)) : 0.0f;
    const float fk = 2.0f * g / denom;
    // source coefficient
    const float bk = (2.0f / 129.0f) *
                     sinpif((float)((m * (SRC_XD + 1)) % 258) / 129.0f);

    v2f C1v; C1v.x = C1s; C1v.y = C1s;
    v2f C3v; C3v.x = C3s; C3v.y = C3s;
    v2f C2v; C2v.x = C2s; C2v.y = C2s;
    v2f fv;  fv.x = fk;  fv.y = fk;
    v2f zz;  zz.x = 0.0f; zz.y = 0.0f;
    v2f svec = zz; if (l == (SRC_YD >> 1)) svec.x = bk;   // col 64 = lane32.x

    // probes (int32 pairs; JAX int64 demotes to int32 without x64)
    const int px0 = probes[0] & 127, py0 = probes[1] & 127;
    const int px1 = probes[2] & 127, py1 = probes[3] & 127;
    const int px2 = probes[4] & 127, py2 = probes[5] & 127;
    const int px3 = probes[6] & 127, py3 = probes[7] & 127;
    if (l == 0) {
        lwx[wid][0] = sinpif((float)((m * (px0 + 1)) % 258) / 129.0f);
        lwx[wid][1] = sinpif((float)((m * (px1 + 1)) % 258) / 129.0f);
        lwx[wid][2] = sinpif((float)((m * (px2 + 1)) % 258) / 129.0f);
        lwx[wid][3] = sinpif((float)((m * (px3 + 1)) % 258) / 129.0f);
    }
    const int pyl0 = __builtin_amdgcn_readfirstlane(py0 >> 1), pel0 = py0 & 1;
    const int pyl1 = __builtin_amdgcn_readfirstlane(py1 >> 1), pel1 = py1 & 1;
    const int pyl2 = __builtin_amdgcn_readfirstlane(py2 >> 1), pel2 = py2 & 1;
    const int pyl3 = __builtin_amdgcn_readfirstlane(py3 >> 1), pel3 = py3 & 1;

    __syncthreads();

    v2f u = zz, uo = zz;
    v2f xc; xc.x = xls[0]; xc.y = xls[1];
    float tr0 = 0.0f, tr1 = 0.0f, tr2 = 0.0f, tr3 = 0.0f;

    // one step + register trace capture: readlane (probe column, uniform lane)
    // -> SGPR broadcast, predicated move into lane tl_. Zero memory traffic.
#define SSTEP(xv, tl_) { \
    const float lf = dpp_from_lower(u.y); \
    const float rt = dpp_from_upper(u.x); \
    v2f cross; cross.x = lf + u.y; cross.y = u.x + rt; \
    const v2f r = C1v * u + C3v * cross + C2v * uo + svec * (xv) + fv; \
    uo = u; u = r; \
    lane_store(tr0, pel0 ? u.y : u.x, pyl0, (tl_), l); \
    lane_store(tr1, pel1 ? u.y : u.x, pyl1, (tl_), l); \
    lane_store(tr2, pel2 ? u.y : u.x, pyl2, (tl_), l); \
    lane_store(tr3, pel3 ? u.y : u.x, pyl3, (tl_), l); \
}

#pragma unroll 1
    for (int t = 0; t < T_STEPSD; t += 2) {
        const v2f xn = *(const v2f*)&xls[t + 2];   // 2-ahead: hides ds latency
        const int tl = t & 63;
        SSTEP(xc.x, tl)
        SSTEP(xc.y, tl + 1)
        xc = xn;
        if (tl == 62) {                            // chunk (t>>6) complete
            const int ch = t >> 6;
            ltr[wid][0][ch][l] = tr0;
            ltr[wid][1][ch][l] = tr1;
            ltr[wid][2][ch][l] = tr2;
            ltr[wid][3][ch][l] = tr3;
        }
    }
#undef SSTEP

    __syncthreads();

    // Block-level reduce over its 4 modes (wx-weighted), then one atomic
    // burst per (probe,chunk) into the 8-slice buffer. q = blockIdx&31 is
    // block-uniform; slice = q&7 -> 4 blocks contend per address.
    const int slice = (blockIdx.x & 31) & (NSLICE - 1);
#pragma unroll
    for (int r = 0; r < 4; ++r) {
        const int jc = (tid >> 6) + r * 4;         // 0..15
        const int j = jc & 3, ch = jc >> 2;
        float s = lwx[0][j] * ltr[0][j][ch][l]
                + lwx[1][j] * ltr[1][j][ch][l]
                + lwx[2][j] * ltr[2][j][ch][l]
                + lwx[3][j] * ltr[3][j][ch][l];
        __hip_atomic_fetch_add(
            &pbuf[((slice * N_PROBESD + j) * BATCHD + bb) * T_STEPSD + ch * 64 + l],
            s, __ATOMIC_RELAXED, __HIP_MEMORY_SCOPE_AGENT);
    }
}

__global__ void spectral_reduce(const float* __restrict__ pbuf,
                                const int* __restrict__ flag,
                                float* __restrict__ partial) {
    if (*flag != 0) return;
    const int tid = threadIdx.x;       // 1024 threads: 32 (j,b) x 32 lanes
    const int jb = tid >> 5;           // j = jb>>3, b = jb&7
    const int j = jb >> 3, b = jb & 7;
    const int ln = tid & 31;
    float acc = 0.0f;
#pragma unroll
    for (int i = 0; i < 8; ++i) {
        const int t = ln * 8 + i;
        float v = 0.0f;
#pragma unroll
        for (int s = 0; s < NSLICE; ++s)
            v += pbuf[((s * N_PROBESD + j) * BATCHD + b) * T_STEPSD + t];
        acc += v * v;
    }
    for (int off = 16; off; off >>= 1) acc += __shfl_down(acc, off, 32);
    if (ln == 0) partial[b * N_PROBESD + j] = acc;
}

// ================= FALLBACK PATH (arbitrary c): round-4 kernel =================
//   lap = up + dn + {lf + Y.y, Y.x + rt} - 4*Y ;  Z = K*lap + (C2 + K2*Z)
#define ROW(up, dn, Yr, Zr, Kr) { \
    const float lf = dpp_from_lower((Yr).y); \
    const float rt = dpp_from_upper((Yr).x); \
    v2f cross; cross.x = lf + (Yr).y; cross.y = (Yr).x + rt; \
    const v2f lap = (up) + (dn) + cross - 4.0f * (Yr); \
    (Zr) = (Kr) * lap + (C2v + K2v * (Zr)); \
}

#define PSEL8(ro, Z, pv) switch (ro) { \
    case 0: pv = (Z##0); break; case 1: pv = (Z##1); break; \
    case 2: pv = (Z##2); break; case 3: pv = (Z##3); break; \
    case 4: pv = (Z##4); break; case 5: pv = (Z##5); break; \
    case 6: pv = (Z##6); break; default: pv = (Z##7); break; }

#define STEP8(Y, Z, tt, xsv) { \
    const int buf_ = (tt) & 1, nb_ = buf_ ^ 1; \
    const v2f ra = *(const v2f*)&haloBot[buf_][wa][colb]; \
    const v2f rb = *(const v2f*)&haloTop[buf_][wb][colb]; \
    ROW(Y##1,  Y##3,  Y##2,  Z##2,  k2) \
    ROW(Y##2,  Y##4,  Y##3,  Z##3,  k3) \
    ROW(Y##3,  Y##5,  Y##4,  Z##4,  k4) \
    ROW(ra,    Y##1,  Y##0,  Z##0,  k0) \
    if (has_src) { if (own_src) (Z##0).x += (xsv); } \
    *(v2f*)&haloTop[nb_][w][colb] = (Z##0); \
    ROW(Y##6,  rb,    Y##7,  Z##7,  k7) \
    *(v2f*)&haloBot[nb_][w][colb] = (Z##7); \
    ROW(Y##0,  Y##2,  Y##1,  Z##1,  k1) \
    ROW(Y##4,  Y##6,  Y##5,  Z##5,  k5) \
    ROW(Y##5,  Y##7,  Y##6,  Z##6,  k6) \
    if (anyprobe) { \
        acc8_0 += (Z##0) * (Z##0); acc8_1 += (Z##1) * (Z##1); \
        acc8_2 += (Z##2) * (Z##2); acc8_3 += (Z##3) * (Z##3); \
        acc8_4 += (Z##4) * (Z##4); acc8_5 += (Z##5) * (Z##5); \
        acc8_6 += (Z##6) * (Z##6); acc8_7 += (Z##7) * (Z##7); \
    } \
    __syncthreads(); \
}

__global__ __launch_bounds__(1024, 4) void wave_sim_full(
        const float* __restrict__ x, const float* __restrict__ c,
        const int* __restrict__ probes, float* __restrict__ partial,
        const int* __restrict__ flag)
{
    if (flag && *flag == 0) return;     // spectral path handled it

    __shared__ float haloTop[2][17][NYD];
    __shared__ float haloBot[2][17][NYD];
    __shared__ float xs[T_STEPSD];

    const int tid = threadIdx.x;
    const int w = tid >> 6;
    const int l = tid & 63;
    const int b = blockIdx.x;

    const float dt = 0.5f, bdamp = 0.005f;
    const float denom = 1.0f / (dt * dt) + 0.5f * bdamp / dt;
    const float inv_denom = 1.0f / denom;
    const float C2 = 2.0f * inv_denom;
    const float K2 = (-1.0f - dt * bdamp) * inv_denom;
    const float KL = dt * dt * inv_denom;
    v2f C2v; C2v.x = C2; C2v.y = C2;
    v2f K2v; K2v.x = K2; K2v.y = K2;

    for (int i = tid; i < 2 * 17 * NYD; i += 1024) {
        ((float*)haloTop)[i] = 0.0f;
        ((float*)haloBot)[i] = 0.0f;
    }
    if (tid < T_STEPSD) xs[tid] = x[tid * BATCHD + b];

    const int rowbase = w * 8;
    const int colb = 2 * l;
#define LOADK(r) \
    v2f k##r; { \
        const v2f cc = *(const v2f*)&c[(rowbase + r) * NYD + colb]; \
        k##r = KL * cc * cc; \
    }
    LOADK(0) LOADK(1) LOADK(2) LOADK(3) LOADK(4) LOADK(5) LOADK(6) LOADK(7)
#undef LOADK

    v2f zz; zz.x = 0.0f; zz.y = 0.0f;
    v2f a0 = zz, a1 = zz, a2 = zz, a3 = zz, a4 = zz, a5 = zz, a6 = zz, a7 = zz;
    v2f b0 = zz, b1 = zz, b2 = zz, b3 = zz, b4 = zz, b5 = zz, b6 = zz, b7 = zz;
    v2f acc8_0 = zz, acc8_1 = zz, acc8_2 = zz, acc8_3 = zz,
        acc8_4 = zz, acc8_5 = zz, acc8_6 = zz, acc8_7 = zz;

    const int px0 = probes[0] & 127, py0 = probes[1] & 127;
    const int px1 = probes[2] & 127, py1 = probes[3] & 127;
    const int px2 = probes[4] & 127, py2 = probes[5] & 127;
    const int px3 = probes[6] & 127, py3 = probes[7] & 127;
    const bool own0 = ((px0 >> 3) == w) && ((py0 >> 1) == l);
    const bool own1 = ((px1 >> 3) == w) && ((py1 >> 1) == l);
    const bool own2 = ((px2 >> 3) == w) && ((py2 >> 1) == l);
    const bool own3 = ((px3 >> 3) == w) && ((py3 >> 1) == l);
    const bool anyprobe = __ballot(own0 | own1 | own2 | own3) != 0ULL;
    const int pro0s = __builtin_amdgcn_readfirstlane(px0 & 7);
    const int pro1s = __builtin_amdgcn_readfirstlane(px1 & 7);
    const int pro2s = __builtin_amdgcn_readfirstlane(px2 & 7);
    const int pro3s = __builtin_amdgcn_readfirstlane(px3 & 7);
    const int pel0 = py0 & 1, pel1 = py1 & 1, pel2 = py2 & 1, pel3 = py3 & 1;

    const bool has_src = (w == (SRC_XD >> 3));
    const bool own_src = has_src && (l == (SRC_YD >> 1));

    const int wa = (w == 0) ? 16 : w - 1;
    const int wb = (w == 15) ? 16 : w + 1;

    __syncthreads();

#pragma unroll 1
    for (int t = 0; t < T_STEPSD; t += 2) {
        const v2f xp = *(const v2f*)&xs[t];
        STEP8(a, b, t, xp.x)
        STEP8(b, a, t + 1, xp.y)
    }

    if (own0) { v2f pv; PSEL8(pro0s, acc8_, pv) partial[b * N_PROBESD + 0] = pel0 ? pv.y : pv.x; }
    if (own1) { v2f pv; PSEL8(pro1s, acc8_, pv) partial[b * N_PROBESD + 1] = pel1 ? pv.y : pv.x; }
    if (own2) { v2f pv; PSEL8(pro2s, acc8_, pv) partial[b * N_PROBESD + 2] = pel2 ? pv.y : pv.x; }
    if (own3) { v2f pv; PSEL8(pro3s, acc8_, pv) partial[b * N_PROBESD + 3] = pel3 ? pv.y : pv.x; }
}

__global__ void reduce_k(const float* __restrict__ partial, float* __restrict__ out) {
    const int p = threadIdx.x;
    if (p < N_PROBESD) {
        float s = 0.0f, tot = 0.0f;
        for (int bb = 0; bb < BATCHD; ++bb) s += partial[bb * N_PROBESD + p];
        for (int i = 0; i < BATCHD * N_PROBESD; ++i) tot += partial[i];
        out[p] = s / tot;
    }
}

// d_ws layout (spectral path):
//   [0..4) flag | [256..262400) pbuf (8*4*8*256 f32 = 256KB) | then partial (32 f32)
// r5/r7 proved ws_size >= this need, so the spectral branch is taken.
extern "C" void kernel_launch(void* const* d_in, const int* in_sizes, int n_in,
                              void* d_out, int out_size, void* d_ws, size_t ws_size,
                              hipStream_t stream) {
    const float* x      = (const float*)d_in[0];
    const float* c      = (const float*)d_in[1];
    const int*   probes = (const int*)d_in[2];
    float* out = (float*)d_out;

    const size_t pbuf_off = 256;
    const size_t pbuf_bytes = (size_t)NSLICE * N_PROBESD * BATCHD * T_STEPSD * sizeof(float);
    const size_t part_off = pbuf_off + pbuf_bytes;
    const size_t need = part_off + 32 * sizeof(float);
    if (ws_size >= need) {
        int*   flag    = (int*)d_ws;
        float* pbuf    = (float*)((char*)d_ws + pbuf_off);
        float* partial = (float*)((char*)d_ws + part_off);
        (void)hipMemsetAsync(d_ws, 0, need, stream);      // flag + pbuf + partial
        check_c<<<64, 256, 0, stream>>>(c, flag);
        spectral_evolve<<<256, 256, 0, stream>>>(x, probes, flag, pbuf);
        spectral_reduce<<<1, 1024, 0, stream>>>(pbuf, flag, partial);
        wave_sim_full<<<BATCHD, 1024, 0, stream>>>(x, c, probes, partial, flag);
        reduce_k<<<1, 64, 0, stream>>>(partial, out);
    } else {
        float* partial = (float*)d_ws;
        wave_sim_full<<<BATCHD, 1024, 0, stream>>>(x, c, probes, partial, nullptr);
        reduce_k<<<1, 64, 0, stream>>>(partial, out);
    }
}